// Round 1
// baseline (378.292 us; speedup 1.0000x reference)
//
#include <hip/hip_runtime.h>
#include <stdint.h>

// ---------------------------------------------------------------------------
// LIL loss, fused. Shapes: b=1024, N=32768, d=128 (d hard-coded).
// ws layout (b rows): u64 maxbits[b] | f32 suml[b] | f32 sumexp[b] | u32 cnt[b] | u32 wrong[b]
// ---------------------------------------------------------------------------

__device__ __forceinline__ unsigned fbits_order(float f) {
    unsigned u = __float_as_uint(f);
    return (u & 0x80000000u) ? ~u : (u | 0x80000000u);
}
__device__ __forceinline__ float order_fbits(unsigned x) {
    unsigned u = (x & 0x80000000u) ? (x & 0x7FFFFFFFu) : ~x;
    return __uint_as_float(u);
}

__global__ void init_ws_kernel(unsigned* w, int nwords) {
    int i = blockIdx.x * blockDim.x + threadIdx.x;
    if (i < nwords) w[i] = 0u;
}

// PASS 0: accumulate per-row {argmax(dot) packed u64, sum exp(l) over qf!=-1,
//          sum l over mask, count mask}.
// PASS 1: fallback exact wrong_cnt for rows where the revise upper-bound can
//          exceed 10 (early-exits otherwise).
template <int PASS>
__global__ __launch_bounds__(256) void pass_kernel(
    const float* __restrict__ Q, const float* __restrict__ Kv,
    const int* __restrict__ flags, const int* __restrict__ qf,
    unsigned long long* __restrict__ maxbits, float* __restrict__ sumlA,
    float* __restrict__ sumexpA, unsigned* __restrict__ cntA,
    unsigned* __restrict__ wrongA, int N)
{
    __shared__ __align__(16) float aT[128 * 64];
    __shared__ __align__(16) float bT[128 * 64];
    const int tid = threadIdx.x;
    const int c0 = blockIdx.x * 64;
    const int r0 = blockIdx.y * 64;
    const float inv_t = 1.0f / 0.07f;

    if (PASS == 1) {
        __shared__ int sAny;
        if (tid == 0) sAny = 0;
        __syncthreads();
        if (tid < 64) {
            unsigned c = cntA[r0 + tid];
            float ub = (float)c / ((float)(N - (int)c) + 1e-6f);
            if (ub > 10.0f) sAny = 1;
        }
        __syncthreads();
        if (sAny == 0) return;  // uniform exit: no row in this tile can revise
    }

    // ---- stage A(Q rows) and B(queue rows) into chunk-transposed swizzled LDS
    // element (k, r) -> idx = k*64 + (((r>>2) ^ (k&15))<<2) + (r&3)
    {
        const float4* Q4 = reinterpret_cast<const float4*>(Q + (size_t)r0 * 128);
        const float4* B4 = reinterpret_cast<const float4*>(Kv + (size_t)c0 * 128);
        for (int it = 0; it < 8; ++it) {
            int idx4 = tid + it * 256;      // 64 rows * 32 float4 chunks
            int r = idx4 >> 5, k4 = idx4 & 31;
            float4 va = Q4[r * 32 + k4];
            float4 vb = B4[r * 32 + k4];
            float va4[4] = {va.x, va.y, va.z, va.w};
            float vb4[4] = {vb.x, vb.y, vb.z, vb.w};
#pragma unroll
            for (int j = 0; j < 4; ++j) {
                int k = 4 * k4 + j;
                int idx = k * 64 + ((((r >> 2) ^ (k & 15)) << 2) | (r & 3));
                aT[idx] = va4[j];
                bT[idx] = vb4[j];
            }
        }
    }
    __syncthreads();

    const int tr = tid >> 4, tc = tid & 15;
    float acc[4][4] = {};
#pragma unroll 8
    for (int k = 0; k < 128; ++k) {
        const float4 av = *reinterpret_cast<const float4*>(
            &aT[k * 64 + ((tr ^ (k & 15)) << 2)]);
        const float4 bv = *reinterpret_cast<const float4*>(
            &bT[k * 64 + ((tc ^ (k & 15)) << 2)]);
        float aa[4] = {av.x, av.y, av.z, av.w};
        float bb[4] = {bv.x, bv.y, bv.z, bv.w};
#pragma unroll
        for (int i = 0; i < 4; ++i)
#pragma unroll
            for (int j = 0; j < 4; ++j) acc[i][j] += aa[i] * bb[j];
    }

    int fl[4], qv[4];
#pragma unroll
    for (int i = 0; i < 4; ++i) fl[i] = flags[r0 + 4 * tr + i];
#pragma unroll
    for (int j = 0; j < 4; ++j) qv[j] = qf[c0 + 4 * tc + j];

    if (PASS == 0) {
#pragma unroll
        for (int i = 0; i < 4; ++i) {
            float best = acc[i][0];
            int bidx = c0 + 4 * tc;
            float se = 0.f, sl = 0.f;
            int cm = 0;
#pragma unroll
            for (int j = 0; j < 4; ++j) {
                float dot = acc[i][j];
                int col = c0 + 4 * tc + j;
                if (j > 0 && (dot > best || (dot == best && col > bidx))) {
                    best = dot; bidx = col;
                }
                float l = dot * inv_t;
                float e = expf(l);
                if (qv[j] != -1) se += e;
                bool mask = (fl[i] == qv[j]) && (fl[i] != -1);
                if (mask) { sl += l; cm++; }
            }
            // reduce across the 16 tc lanes of this row group
#pragma unroll
            for (int off = 1; off < 16; off <<= 1) {
                float ob = __shfl_xor(best, off);
                int oi = __shfl_xor(bidx, off);
                if (ob > best || (ob == best && oi > bidx)) { best = ob; bidx = oi; }
                se += __shfl_xor(se, off);
                sl += __shfl_xor(sl, off);
                cm += __shfl_xor(cm, off);
            }
            if (tc == 0) {
                int r = r0 + 4 * tr + i;
                unsigned long long pack =
                    ((unsigned long long)fbits_order(best) << 32) | (unsigned)bidx;
                atomicMax(&maxbits[r], pack);
                atomicAdd(&sumexpA[r], se);
                atomicAdd(&sumlA[r], sl);
                atomicAdd(&cntA[r], (unsigned)cm);
            }
        }
    } else {
#pragma unroll
        for (int i = 0; i < 4; ++i) {
            int r = r0 + 4 * tr + i;
            unsigned long long mb = maxbits[r];
            float m = order_fbits((unsigned)(mb >> 32)) * inv_t;
            float cf = (float)cntA[r];
            float mean = (sumlA[r] - cf * m) * (1.0f / (float)N);
            int wp = 0;
#pragma unroll
            for (int j = 0; j < 4; ++j) {
                float l = acc[i][j] * inv_t;
                bool mask = (fl[i] == qv[j]) && (fl[i] != -1);
                float lfp = mask ? (l - m) : 0.f;
                if (lfp < mean) wp++;
            }
#pragma unroll
            for (int off = 1; off < 16; off <<= 1) wp += __shfl_xor(wp, off);
            if (tc == 0) atomicAdd(&wrongA[r], (unsigned)wp);
        }
    }
}

__global__ void final_kernel(const int* __restrict__ flags,
                             const int* __restrict__ qf,
                             const int* __restrict__ n_iter_p,
                             const unsigned long long* __restrict__ maxbits,
                             const float* __restrict__ sumlA,
                             const float* __restrict__ sumexpA,
                             const unsigned* __restrict__ cntA,
                             const unsigned* __restrict__ wrongA,
                             float* __restrict__ out, int N, int b)
{
    __shared__ float redf[1024];
    __shared__ unsigned redu[1024];
    const int r = threadIdx.x;
    const float inv_t = 1.0f / 0.07f;

    int fl = flags[r];
    unsigned long long mb = maxbits[r];
    float m = order_fbits((unsigned)(mb >> 32)) * inv_t;
    int jmax = (int)(mb & 0xFFFFFFFFull);
    float suml = sumlA[r];
    float sumexp = sumexpA[r];
    unsigned cnt = cntA[r];
    bool row_m1 = (fl == -1);
    int qmax = qf[jmax];

    float rowsum;
    if (row_m1) {
        rowsum = 0.f;   // entire row zeroed -> every exp==1 -> all excluded
    } else {
        float adj = sumexp;
        if (qmax != -1) adj -= expf(m);  // exclude argmax (exp(l-m)==1)
        rowsum = expf(-m) * adj;
        rowsum = fmaxf(rowsum, 0.f);
    }
    float sum_lfp = suml - (float)cnt * m;
    unsigned nnz = cnt - ((!row_m1 && fl == qmax) ? 1u : 0u);

    int nit = *n_iter_p;
    bool revise = false;
    if (nit >= 0) {
        float ub = (float)cnt / ((float)(N - (int)cnt) + 1e-6f);
        if (ub > 10.0f) {  // only then can the true ratio exceed 10
            unsigned wr = wrongA[r];
            float wf = (float)wr;
            float pf = (float)(N - (int)wr);
            revise = (wf / (pf + 1e-6f)) > 10.0f;
        }
    }
    out[1 + r] = (float)(revise ? 0 : fl);
    float eff_suml = revise ? 0.f : sum_lfp;
    unsigned eff_nnz = revise ? 0u : nnz;

    // reduce num_nonzero (exact integer)
    redu[r] = eff_nnz;
    __syncthreads();
    for (int s = 512; s > 0; s >>= 1) {
        if (r < s) redu[r] += redu[r + s];
        __syncthreads();
    }
    unsigned total_nnz = redu[0];
    __syncthreads();

    float row_lp = eff_suml - (float)N * logf(rowsum + 1e-12f);
    float contrib = (total_nnz > 0u && rowsum > 0.f && row_lp < 0.f)
                        ? row_lp / (float)total_nnz
                        : 0.f;
    redf[r] = contrib;
    __syncthreads();
    for (int s = 512; s > 0; s >>= 1) {
        if (r < s) redf[r] += redf[r + s];
        __syncthreads();
    }
    if (r == 0) out[0] = -(redf[0] / (float)b);  // TEMP/BASE_TEMP == 1
}

extern "C" void kernel_launch(void* const* d_in, const int* in_sizes, int n_in,
                              void* d_out, int out_size, void* d_ws,
                              size_t ws_size, hipStream_t stream)
{
    const float* Q = (const float*)d_in[0];
    const float* Kall = (const float*)d_in[1];
    const int* flags = (const int*)d_in[2];
    const int* qfall = (const int*)d_in[3];
    const int* n_iter = (const int*)d_in[4];
    float* out = (float*)d_out;

    const int b = in_sizes[2];          // 1024
    const int total = in_sizes[3];      // 33792
    const int N = total - b;            // 32768
    const float* Kv = Kall + (size_t)b * 128;
    const int* qf = qfall + b;

    char* wsb = (char*)d_ws;
    unsigned long long* maxbits = (unsigned long long*)wsb;
    float* sumlA = (float*)(wsb + (size_t)b * 8);
    float* sumexpA = (float*)(wsb + (size_t)b * 12);
    unsigned* cntA = (unsigned*)(wsb + (size_t)b * 16);
    unsigned* wrongA = (unsigned*)(wsb + (size_t)b * 20);

    const int nwords = b * 6;  // u64 + 4 * u32 per row
    init_ws_kernel<<<(nwords + 255) / 256, 256, 0, stream>>>((unsigned*)wsb,
                                                             nwords);
    dim3 grid(N / 64, b / 64);
    pass_kernel<0><<<grid, 256, 0, stream>>>(Q, Kv, flags, qf, maxbits, sumlA,
                                             sumexpA, cntA, wrongA, N);
    pass_kernel<1><<<grid, 256, 0, stream>>>(Q, Kv, flags, qf, maxbits, sumlA,
                                             sumexpA, cntA, wrongA, N);
    final_kernel<<<1, b, 0, stream>>>(flags, qf, n_iter, maxbits, sumlA,
                                      sumexpA, cntA, wrongA, out, N, b);
}

// Round 2
// 206.028 us; speedup vs baseline: 1.8361x; 1.8361x over previous
//
#include <hip/hip_runtime.h>
#include <stdint.h>

// ---------------------------------------------------------------------------
// LIL loss, fused, bf16-MFMA dot engine. Shapes: b=1024, N=32768, d=128.
// ws: [u64 maxbits[b] | f32 suml[b] | f32 sumexp[b] | u32 cnt[b] | u32 wrong[b]]
//     then (if room) [bf16 Kv: N*128] [bf16 Q: b*128]
// ---------------------------------------------------------------------------

typedef short bf16x8 __attribute__((ext_vector_type(8)));
typedef unsigned short ushort8v __attribute__((ext_vector_type(8)));
typedef float f32x4 __attribute__((ext_vector_type(4)));

__device__ __forceinline__ unsigned fbits_order(float f) {
    unsigned u = __float_as_uint(f);
    return (u & 0x80000000u) ? ~u : (u | 0x80000000u);
}
__device__ __forceinline__ float order_fbits(unsigned x) {
    unsigned u = (x & 0x80000000u) ? (x & 0x7FFFFFFFu) : ~x;
    return __uint_as_float(u);
}
__device__ __forceinline__ unsigned short f2bf(float x) {
    unsigned u = __float_as_uint(x);
    return (unsigned short)((u + 0x7FFFu + ((u >> 16) & 1u)) >> 16);
}

__global__ void init_ws_kernel(unsigned* w, int nwords) {
    int i = blockIdx.x * blockDim.x + threadIdx.x;
    if (i < nwords) w[i] = 0u;
}

__global__ void convert_kernel(const float* __restrict__ src,
                               unsigned short* __restrict__ dst, int n8) {
    int i = blockIdx.x * blockDim.x + threadIdx.x;
    if (i >= n8) return;
    const float4* s4 = reinterpret_cast<const float4*>(src) + 2 * (size_t)i;
    float4 a = s4[0], b = s4[1];
    ushort8v v;
    v[0] = f2bf(a.x); v[1] = f2bf(a.y); v[2] = f2bf(a.z); v[3] = f2bf(a.w);
    v[4] = f2bf(b.x); v[5] = f2bf(b.y); v[6] = f2bf(b.z); v[7] = f2bf(b.w);
    *reinterpret_cast<ushort8v*>(dst + 8 * (size_t)i) = v;
}

// Main fused kernel: C-tile 64(rows) x 128(cols), full K=128 in LDS (bf16).
template <bool USE_WS>
__global__ __launch_bounds__(256) void gemm_kernel(
    const float* __restrict__ Qf, const float* __restrict__ Kf,
    const unsigned short* __restrict__ Qb, const unsigned short* __restrict__ Kb,
    const int* __restrict__ flags, const int* __restrict__ qf,
    unsigned long long* __restrict__ maxbits, float* __restrict__ sumlA,
    float* __restrict__ sumexpA, unsigned* __restrict__ cntA, int N)
{
    __shared__ __align__(16) unsigned short sA[64 * 128];    // 16 KB, swizzled
    __shared__ __align__(16) unsigned short sB[128 * 128];   // 32 KB, swizzled
    __shared__ int sFl[64];
    __shared__ int sQf[128];

    const int tid = threadIdx.x;
    const int c0 = blockIdx.x * 128;
    const int r0 = blockIdx.y * 64;
    const float inv_t = 1.0f / 0.07f;

    char* sAb = (char*)sA;
    char* sBb = (char*)sB;

    // ---- stage A (Q rows r0..r0+63), 1024 chunks of 8 bf16
    for (int it = 0; it < 4; ++it) {
        int c = tid + it * 256;
        int row = c >> 4, kc = c & 15;
        int off = (row * 256 + kc * 16) ^ ((row & 7) << 4);
        if (USE_WS) {
            ushort8v v = *reinterpret_cast<const ushort8v*>(
                Qb + (size_t)(r0 + row) * 128 + kc * 8);
            *reinterpret_cast<ushort8v*>(sAb + off) = v;
        } else {
            const float4* s4 = reinterpret_cast<const float4*>(
                Qf + (size_t)(r0 + row) * 128 + kc * 8);
            float4 a = s4[0], b = s4[1];
            ushort8v v;
            v[0] = f2bf(a.x); v[1] = f2bf(a.y); v[2] = f2bf(a.z); v[3] = f2bf(a.w);
            v[4] = f2bf(b.x); v[5] = f2bf(b.y); v[6] = f2bf(b.z); v[7] = f2bf(b.w);
            *reinterpret_cast<ushort8v*>(sAb + off) = v;
        }
    }
    // ---- stage B (K rows c0..c0+127), 2048 chunks
    for (int it = 0; it < 8; ++it) {
        int c = tid + it * 256;
        int row = c >> 4, kc = c & 15;
        int off = (row * 256 + kc * 16) ^ ((row & 7) << 4);
        if (USE_WS) {
            ushort8v v = *reinterpret_cast<const ushort8v*>(
                Kb + (size_t)(c0 + row) * 128 + kc * 8);
            *reinterpret_cast<ushort8v*>(sBb + off) = v;
        } else {
            const float4* s4 = reinterpret_cast<const float4*>(
                Kf + (size_t)(c0 + row) * 128 + kc * 8);
            float4 a = s4[0], b = s4[1];
            ushort8v v;
            v[0] = f2bf(a.x); v[1] = f2bf(a.y); v[2] = f2bf(a.z); v[3] = f2bf(a.w);
            v[4] = f2bf(b.x); v[5] = f2bf(b.y); v[6] = f2bf(b.z); v[7] = f2bf(b.w);
            *reinterpret_cast<ushort8v*>(sBb + off) = v;
        }
    }
    if (tid < 64) sFl[tid] = flags[r0 + tid];
    if (tid < 128) sQf[tid] = qf[c0 + tid];
    __syncthreads();

    const int lane = tid & 63;
    const int g = lane >> 4;      // k-group
    const int q = lane & 15;      // row (A) / col (B) within fragment
    const int wave = tid >> 6;
    const int wr = wave >> 1;     // 0..1: row half
    const int wc = wave & 1;      // 0..1: col half

    f32x4 acc[2][4] = {};
#pragma unroll
    for (int ks = 0; ks < 4; ++ks) {
        const int kb = ks * 64 + g * 16;
        bf16x8 af[2];
#pragma unroll
        for (int mi = 0; mi < 2; ++mi) {
            int row = 32 * wr + 16 * mi + q;
            int off = (row * 256 + kb) ^ ((q & 7) << 4);
            af[mi] = *reinterpret_cast<const bf16x8*>(sAb + off);
        }
        bf16x8 bf[4];
#pragma unroll
        for (int ni = 0; ni < 4; ++ni) {
            int col = 64 * wc + 16 * ni + q;
            int off = (col * 256 + kb) ^ ((q & 7) << 4);
            bf[ni] = *reinterpret_cast<const bf16x8*>(sBb + off);
        }
#pragma unroll
        for (int mi = 0; mi < 2; ++mi)
#pragma unroll
            for (int ni = 0; ni < 4; ++ni)
                acc[mi][ni] = __builtin_amdgcn_mfma_f32_16x16x32_bf16(
                    af[mi], bf[ni], acc[mi][ni], 0, 0, 0);
    }

    // epilogue: per output row, reduce {argmax, sum exp, sum l(masked), cnt}
    int qv[4];
#pragma unroll
    for (int ni = 0; ni < 4; ++ni) qv[ni] = sQf[64 * wc + 16 * ni + q];

#pragma unroll
    for (int mi = 0; mi < 2; ++mi) {
#pragma unroll
        for (int reg = 0; reg < 4; ++reg) {
            int rl = 32 * wr + 16 * mi + 4 * g + reg;
            int fl = sFl[rl];
            float best = acc[mi][0][reg];
            int bidx = c0 + 64 * wc + q;
            float se = 0.f, sl = 0.f;
            int cm = 0;
#pragma unroll
            for (int ni = 0; ni < 4; ++ni) {
                float dot = acc[mi][ni][reg];
                int col = c0 + 64 * wc + 16 * ni + q;
                if (ni > 0 && (dot > best || (dot == best && col > bidx))) {
                    best = dot; bidx = col;
                }
                float l = dot * inv_t;
                float e = __expf(l);
                if (qv[ni] != -1) se += e;
                if (fl == qv[ni] && fl != -1) { sl += l; cm++; }
            }
#pragma unroll
            for (int off = 1; off < 16; off <<= 1) {
                float ob = __shfl_xor(best, off);
                int oi = __shfl_xor(bidx, off);
                if (ob > best || (ob == best && oi > bidx)) { best = ob; bidx = oi; }
                se += __shfl_xor(se, off);
                sl += __shfl_xor(sl, off);
                cm += __shfl_xor(cm, off);
            }
            if (q == 0) {
                int r = r0 + rl;
                unsigned long long pack =
                    ((unsigned long long)fbits_order(best) << 32) | (unsigned)bidx;
                atomicMax(&maxbits[r], pack);
                atomicAdd(&sumexpA[r], se);
                atomicAdd(&sumlA[r], sl);
                atomicAdd(&cntA[r], (unsigned)cm);
            }
        }
    }
}

// Exact wrong_cnt fallback; early-exits unless a row can possibly revise
// (requires cnt/(N-cnt) > 10; actual data has ~200x margin, so this is
// correctness insurance only). f32 recompute from global if triggered.
__global__ void fallback_kernel(const float* __restrict__ Q,
                                const float* __restrict__ Kv,
                                const int* __restrict__ flags,
                                const int* __restrict__ qf,
                                const unsigned long long* __restrict__ maxbits,
                                const float* __restrict__ sumlA,
                                const unsigned* __restrict__ cntA,
                                unsigned* __restrict__ wrongA, int N)
{
    const int r = blockIdx.x;
    unsigned c = cntA[r];
    float ub = (float)c / ((float)(N - (int)c) + 1e-6f);
    if (!(ub > 10.0f)) return;

    __shared__ float sQ[128];
    const int tid = threadIdx.x;
    if (tid < 128) sQ[tid] = Q[(size_t)r * 128 + tid];
    __syncthreads();

    const float inv_t = 1.0f / 0.07f;
    float m = order_fbits((unsigned)(maxbits[r] >> 32)) * inv_t;
    float mean = (sumlA[r] - (float)c * m) / (float)N;
    int fl = flags[r];
    int wp = 0;
    for (int j = tid; j < N; j += 256) {
        float dot = 0.f;
        const float* kr = Kv + (size_t)j * 128;
        for (int k = 0; k < 128; ++k) dot += sQ[k] * kr[k];
        bool mask = (fl == qf[j]) && (fl != -1);
        float lfp = mask ? (dot * inv_t - m) : 0.f;
        if (lfp < mean) wp++;
    }
    atomicAdd(&wrongA[r], (unsigned)wp);
}

__global__ void final_kernel(const int* __restrict__ flags,
                             const int* __restrict__ qf,
                             const int* __restrict__ n_iter_p,
                             const unsigned long long* __restrict__ maxbits,
                             const float* __restrict__ sumlA,
                             const float* __restrict__ sumexpA,
                             const unsigned* __restrict__ cntA,
                             const unsigned* __restrict__ wrongA,
                             float* __restrict__ out, int N, int b)
{
    __shared__ float redf[1024];
    __shared__ unsigned redu[1024];
    const int r = threadIdx.x;
    const float inv_t = 1.0f / 0.07f;

    int fl = flags[r];
    unsigned long long mb = maxbits[r];
    float m = order_fbits((unsigned)(mb >> 32)) * inv_t;
    int jmax = (int)(mb & 0xFFFFFFFFull);
    float suml = sumlA[r];
    float sumexp = sumexpA[r];
    unsigned cnt = cntA[r];
    bool row_m1 = (fl == -1);
    int qmax = qf[jmax];

    float rowsum;
    if (row_m1) {
        rowsum = 0.f;  // row zeroed -> every exp==1 -> all excluded
    } else {
        float adj = sumexp;
        if (qmax != -1) adj -= __expf(m);  // exclude argmax (exp(l-m)==1)
        rowsum = __expf(-m) * adj;
        rowsum = fmaxf(rowsum, 0.f);
    }
    float sum_lfp = suml - (float)cnt * m;
    unsigned nnz = cnt - ((!row_m1 && fl == qmax) ? 1u : 0u);

    int nit = *n_iter_p;
    bool revise = false;
    if (nit >= 0) {
        float ub = (float)cnt / ((float)(N - (int)cnt) + 1e-6f);
        if (ub > 10.0f) {
            unsigned wr = wrongA[r];
            float wf = (float)wr;
            float pf = (float)(N - (int)wr);
            revise = (wf / (pf + 1e-6f)) > 10.0f;
        }
    }
    out[1 + r] = (float)(revise ? 0 : fl);
    float eff_suml = revise ? 0.f : sum_lfp;
    unsigned eff_nnz = revise ? 0u : nnz;

    redu[r] = eff_nnz;
    __syncthreads();
    for (int s = 512; s > 0; s >>= 1) {
        if (r < s) redu[r] += redu[r + s];
        __syncthreads();
    }
    unsigned total_nnz = redu[0];
    __syncthreads();

    float row_lp = eff_suml - (float)N * logf(rowsum + 1e-12f);
    float contrib = (total_nnz > 0u && rowsum > 0.f && row_lp < 0.f)
                        ? row_lp / (float)total_nnz
                        : 0.f;
    redf[r] = contrib;
    __syncthreads();
    for (int s = 512; s > 0; s >>= 1) {
        if (r < s) redf[r] += redf[r + s];
        __syncthreads();
    }
    if (r == 0) out[0] = -(redf[0] / (float)b);  // TEMP/BASE_TEMP == 1
}

extern "C" void kernel_launch(void* const* d_in, const int* in_sizes, int n_in,
                              void* d_out, int out_size, void* d_ws,
                              size_t ws_size, hipStream_t stream)
{
    const float* Q = (const float*)d_in[0];
    const float* Kall = (const float*)d_in[1];
    const int* flags = (const int*)d_in[2];
    const int* qfall = (const int*)d_in[3];
    const int* n_iter = (const int*)d_in[4];
    float* out = (float*)d_out;

    const int b = in_sizes[2];          // 1024
    const int total = in_sizes[3];      // 33792
    const int N = total - b;            // 32768
    const float* Kv = Kall + (size_t)b * 128;
    const int* qf = qfall + b;

    char* wsb = (char*)d_ws;
    unsigned long long* maxbits = (unsigned long long*)wsb;
    float* sumlA = (float*)(wsb + (size_t)b * 8);
    float* sumexpA = (float*)(wsb + (size_t)b * 12);
    unsigned* cntA = (unsigned*)(wsb + (size_t)b * 16);
    unsigned* wrongA = (unsigned*)(wsb + (size_t)b * 20);

    const size_t accum_bytes = (size_t)b * 24;  // 24 KB
    unsigned short* Kb = (unsigned short*)(wsb + accum_bytes);
    unsigned short* Qb = Kb + (size_t)N * 128;
    const size_t need = accum_bytes + ((size_t)N + b) * 128 * 2;
    const bool use_ws = (ws_size >= need);

    const int nwords = b * 6;
    init_ws_kernel<<<(nwords + 255) / 256, 256, 0, stream>>>((unsigned*)wsb,
                                                             nwords);
    if (use_ws) {
        int n8k = N * 128 / 8;
        convert_kernel<<<(n8k + 255) / 256, 256, 0, stream>>>(Kv, Kb, n8k);
        int n8q = b * 128 / 8;
        convert_kernel<<<(n8q + 255) / 256, 256, 0, stream>>>(Q, Qb, n8q);
    }

    dim3 grid(N / 128, b / 64);
    if (use_ws) {
        gemm_kernel<true><<<grid, 256, 0, stream>>>(Q, Kv, Qb, Kb, flags, qf,
                                                    maxbits, sumlA, sumexpA,
                                                    cntA, N);
    } else {
        gemm_kernel<false><<<grid, 256, 0, stream>>>(Q, Kv, Qb, Kb, flags, qf,
                                                     maxbits, sumlA, sumexpA,
                                                     cntA, N);
    }
    fallback_kernel<<<b, 256, 0, stream>>>(Q, Kv, flags, qf, maxbits, sumlA,
                                           cntA, wrongA, N);
    final_kernel<<<1, b, 0, stream>>>(flags, qf, n_iter, maxbits, sumlA,
                                      sumexpA, cntA, wrongA, out, N, b);
}

// Round 3
// 85.626 us; speedup vs baseline: 4.4180x; 2.4061x over previous
//
#include <hip/hip_runtime.h>
#include <stdint.h>

// ---------------------------------------------------------------------------
// LIL loss, fused bf16-MFMA dot engine, atomic-free partial reduction.
// Shapes: b=1024, N=32768, d=128 (layout constants below assume these).
// ws layout:
//   [0KB)   bestA  f32[b]
//   [4KB)   jmaxA  i32[b]
//   [8KB)   sumlA  f32[b]
//   [12KB)  sumexpA f32[b]
//   [16KB)  cntA   u32[b]
//   [20KB)  wrongA u32[b]
//   [24KB)  tier A/B: partials pbest/pbidx/pse/psl/pcnt (5 x NCB*b x 4B)
//           tier C:   maxbits u64[b]
//   then    tier A:   Kb bf16[N*128]
// ---------------------------------------------------------------------------

typedef short bf16x8 __attribute__((ext_vector_type(8)));
typedef unsigned short ushort8v __attribute__((ext_vector_type(8)));
typedef float f32x4 __attribute__((ext_vector_type(4)));

__device__ __forceinline__ unsigned fbits_order(float f) {
    unsigned u = __float_as_uint(f);
    return (u & 0x80000000u) ? ~u : (u | 0x80000000u);
}
__device__ __forceinline__ float order_fbits(unsigned x) {
    unsigned u = (x & 0x80000000u) ? (x & 0x7FFFFFFFu) : ~x;
    return __uint_as_float(u);
}
__device__ __forceinline__ unsigned short f2bf(float x) {
    unsigned u = __float_as_uint(x);
    return (unsigned short)((u + 0x7FFFu + ((u >> 16) & 1u)) >> 16);
}

__global__ void init_zero_kernel(unsigned* w, int nwords) {
    int i = blockIdx.x * blockDim.x + threadIdx.x;
    if (i < nwords) w[i] = 0u;
}

__global__ void convert_kernel(const float* __restrict__ src,
                               unsigned short* __restrict__ dst, int n8) {
    int i = blockIdx.x * blockDim.x + threadIdx.x;
    if (i >= n8) return;
    const float4* s4 = reinterpret_cast<const float4*>(src) + 2 * (size_t)i;
    float4 a = s4[0], b = s4[1];
    ushort8v v;
    v[0] = f2bf(a.x); v[1] = f2bf(a.y); v[2] = f2bf(a.z); v[3] = f2bf(a.w);
    v[4] = f2bf(b.x); v[5] = f2bf(b.y); v[6] = f2bf(b.z); v[7] = f2bf(b.w);
    *reinterpret_cast<ushort8v*>(dst + 8 * (size_t)i) = v;
}

__global__ void unpack_kernel(const unsigned long long* __restrict__ maxbits,
                              float* __restrict__ bestA, int* __restrict__ jmaxA,
                              int b) {
    int r = blockIdx.x * blockDim.x + threadIdx.x;
    if (r >= b) return;
    unsigned long long mb = maxbits[r];
    bestA[r] = order_fbits((unsigned)(mb >> 32));
    jmaxA[r] = (int)(mb & 0xFFFFFFFFull);
}

// C-tile 64(rows) x 128(cols), full K=128 in LDS (bf16, XOR-swizzled).
template <bool STAGE_WS, bool EPI_ATOMIC>
__global__ __launch_bounds__(256) void gemm_kernel(
    const float* __restrict__ Qf, const float* __restrict__ Kf,
    const unsigned short* __restrict__ Kb,
    const int* __restrict__ flags, const int* __restrict__ qf,
    float* __restrict__ pbest, int* __restrict__ pbidx,
    float* __restrict__ pse, float* __restrict__ psl,
    unsigned* __restrict__ pcnt,
    unsigned long long* __restrict__ maxbits, float* __restrict__ sumlA,
    float* __restrict__ sumexpA, unsigned* __restrict__ cntA,
    int N, int b)
{
    __shared__ __align__(16) unsigned short sA[64 * 128];   // 16 KB swizzled
    __shared__ __align__(16) unsigned short sB[128 * 128];  // 32 KB swizzled
    __shared__ int sFl[64];
    __shared__ int sQf[128];
    __shared__ float sBest[2][64];
    __shared__ int sBidx[2][64];
    __shared__ float sSe[2][64];
    __shared__ float sSl[2][64];
    __shared__ unsigned sCnt[2][64];

    const int tid = threadIdx.x;
    const int c0 = blockIdx.x * 128;
    const int r0 = blockIdx.y * 64;
    const float inv_t = 1.0f / 0.07f;

    char* sAb = (char*)sA;
    char* sBb = (char*)sB;

    // ---- stage A (Q rows r0..r0+63) with in-flight f32->bf16
    for (int it = 0; it < 4; ++it) {
        int c = tid + it * 256;
        int row = c >> 4, kc = c & 15;
        int off = (row * 256 + kc * 16) ^ ((row & 7) << 4);
        const float4* s4 = reinterpret_cast<const float4*>(
            Qf + (size_t)(r0 + row) * 128 + kc * 8);
        float4 a = s4[0], bq = s4[1];
        ushort8v v;
        v[0] = f2bf(a.x); v[1] = f2bf(a.y); v[2] = f2bf(a.z); v[3] = f2bf(a.w);
        v[4] = f2bf(bq.x); v[5] = f2bf(bq.y); v[6] = f2bf(bq.z); v[7] = f2bf(bq.w);
        *reinterpret_cast<ushort8v*>(sAb + off) = v;
    }
    // ---- stage B (K rows c0..c0+127)
    for (int it = 0; it < 8; ++it) {
        int c = tid + it * 256;
        int row = c >> 4, kc = c & 15;
        int off = (row * 256 + kc * 16) ^ ((row & 7) << 4);
        if (STAGE_WS) {
            ushort8v v = *reinterpret_cast<const ushort8v*>(
                Kb + (size_t)(c0 + row) * 128 + kc * 8);
            *reinterpret_cast<ushort8v*>(sBb + off) = v;
        } else {
            const float4* s4 = reinterpret_cast<const float4*>(
                Kf + (size_t)(c0 + row) * 128 + kc * 8);
            float4 a = s4[0], bq = s4[1];
            ushort8v v;
            v[0] = f2bf(a.x); v[1] = f2bf(a.y); v[2] = f2bf(a.z); v[3] = f2bf(a.w);
            v[4] = f2bf(bq.x); v[5] = f2bf(bq.y); v[6] = f2bf(bq.z); v[7] = f2bf(bq.w);
            *reinterpret_cast<ushort8v*>(sBb + off) = v;
        }
    }
    if (tid < 64) sFl[tid] = flags[r0 + tid];
    if (tid < 128) sQf[tid] = qf[c0 + tid];
    __syncthreads();

    const int lane = tid & 63;
    const int g = lane >> 4;   // k-group
    const int q = lane & 15;   // row (A) / col (B) within fragment
    const int wave = tid >> 6;
    const int wr = wave >> 1;  // row half
    const int wc = wave & 1;   // col half

    f32x4 acc[2][4] = {};
#pragma unroll
    for (int ks = 0; ks < 4; ++ks) {
        const int kb = ks * 64 + g * 16;
        bf16x8 af[2];
#pragma unroll
        for (int mi = 0; mi < 2; ++mi) {
            int row = 32 * wr + 16 * mi + q;
            int off = (row * 256 + kb) ^ ((q & 7) << 4);
            af[mi] = *reinterpret_cast<const bf16x8*>(sAb + off);
        }
        bf16x8 bfr[4];
#pragma unroll
        for (int ni = 0; ni < 4; ++ni) {
            int col = 64 * wc + 16 * ni + q;
            int off = (col * 256 + kb) ^ ((q & 7) << 4);
            bfr[ni] = *reinterpret_cast<const bf16x8*>(sBb + off);
        }
#pragma unroll
        for (int mi = 0; mi < 2; ++mi)
#pragma unroll
            for (int ni = 0; ni < 4; ++ni)
                acc[mi][ni] = __builtin_amdgcn_mfma_f32_16x16x32_bf16(
                    af[mi], bfr[ni], acc[mi][ni], 0, 0, 0);
    }

    // epilogue: per output row, 16-lane reduce {argmax, sum exp, sum l, cnt}
    int qv[4];
#pragma unroll
    for (int ni = 0; ni < 4; ++ni) qv[ni] = sQf[64 * wc + 16 * ni + q];

#pragma unroll
    for (int mi = 0; mi < 2; ++mi) {
#pragma unroll
        for (int reg = 0; reg < 4; ++reg) {
            int rl = 32 * wr + 16 * mi + 4 * g + reg;
            int fl = sFl[rl];
            float best = acc[mi][0][reg];
            int bidx = c0 + 64 * wc + q;
            float se = 0.f, sl = 0.f;
            int cm = 0;
#pragma unroll
            for (int ni = 0; ni < 4; ++ni) {
                float dot = acc[mi][ni][reg];
                int col = c0 + 64 * wc + 16 * ni + q;
                if (ni > 0 && (dot > best || (dot == best && col > bidx))) {
                    best = dot; bidx = col;
                }
                float l = dot * inv_t;
                float e = __expf(l);
                if (qv[ni] != -1) se += e;
                if (fl == qv[ni] && fl != -1) { sl += l; cm++; }
            }
#pragma unroll
            for (int off = 1; off < 16; off <<= 1) {
                float ob = __shfl_xor(best, off);
                int oi = __shfl_xor(bidx, off);
                if (ob > best || (ob == best && oi > bidx)) { best = ob; bidx = oi; }
                se += __shfl_xor(se, off);
                sl += __shfl_xor(sl, off);
                cm += __shfl_xor(cm, off);
            }
            if (q == 0) {
                if (EPI_ATOMIC) {
                    int r = r0 + rl;
                    unsigned long long pack =
                        ((unsigned long long)fbits_order(best) << 32) |
                        (unsigned)bidx;
                    atomicMax(&maxbits[r], pack);
                    atomicAdd(&sumexpA[r], se);
                    atomicAdd(&sumlA[r], sl);
                    atomicAdd(&cntA[r], (unsigned)cm);
                } else {
                    sBest[wc][rl] = best;
                    sBidx[wc][rl] = bidx;
                    sSe[wc][rl] = se;
                    sSl[wc][rl] = sl;
                    sCnt[wc][rl] = (unsigned)cm;
                }
            }
        }
    }

    if (!EPI_ATOMIC) {
        __syncthreads();
        if (tid < 64) {
            float b0 = sBest[0][tid], b1 = sBest[1][tid];
            int i0 = sBidx[0][tid], i1 = sBidx[1][tid];
            bool t1 = (b1 > b0) || (b1 == b0 && i1 > i0);
            size_t p = (size_t)blockIdx.x * b + r0 + tid;
            pbest[p] = t1 ? b1 : b0;
            pbidx[p] = t1 ? i1 : i0;
            pse[p] = sSe[0][tid] + sSe[1][tid];
            psl[p] = sSl[0][tid] + sSl[1][tid];
            pcnt[p] = sCnt[0][tid] + sCnt[1][tid];
        }
    }
}

// One block per row: fold NCB (=256) partials with a deterministic tree.
__global__ __launch_bounds__(256) void reduce_kernel(
    const float* __restrict__ pbest, const int* __restrict__ pbidx,
    const float* __restrict__ pse, const float* __restrict__ psl,
    const unsigned* __restrict__ pcnt, float* __restrict__ bestA,
    int* __restrict__ jmaxA, float* __restrict__ sumlA,
    float* __restrict__ sumexpA, unsigned* __restrict__ cntA, int b)
{
    const int r = blockIdx.x;
    const int t = threadIdx.x;  // t == col-block index, 256 of them
    size_t p = (size_t)t * b + r;
    float best = pbest[p];
    int bidx = pbidx[p];
    float se = pse[p];
    float sl = psl[p];
    unsigned cm = pcnt[p];

#pragma unroll
    for (int off = 1; off < 64; off <<= 1) {
        float ob = __shfl_xor(best, off);
        int oi = __shfl_xor(bidx, off);
        if (ob > best || (ob == best && oi > bidx)) { best = ob; bidx = oi; }
        se += __shfl_xor(se, off);
        sl += __shfl_xor(sl, off);
        cm += __shfl_xor(cm, off);
    }
    __shared__ float wB[4], wSe[4], wSl[4];
    __shared__ int wI[4];
    __shared__ unsigned wC[4];
    const int wv = t >> 6;
    if ((t & 63) == 0) {
        wB[wv] = best; wI[wv] = bidx; wSe[wv] = se; wSl[wv] = sl; wC[wv] = cm;
    }
    __syncthreads();
    if (t == 0) {
        best = wB[0]; bidx = wI[0]; se = wSe[0]; sl = wSl[0]; cm = wC[0];
#pragma unroll
        for (int i = 1; i < 4; ++i) {
            if (wB[i] > best || (wB[i] == best && wI[i] > bidx)) {
                best = wB[i]; bidx = wI[i];
            }
            se += wSe[i]; sl += wSl[i]; cm += wC[i];
        }
        bestA[r] = best;
        jmaxA[r] = bidx;
        sumexpA[r] = se;
        sumlA[r] = sl;
        cntA[r] = cm;
    }
}

// Exact wrong_cnt fallback; early-exits unless a row could possibly revise.
__global__ void fallback_kernel(const float* __restrict__ Q,
                                const float* __restrict__ Kv,
                                const int* __restrict__ flags,
                                const int* __restrict__ qf,
                                const float* __restrict__ bestA,
                                const float* __restrict__ sumlA,
                                const unsigned* __restrict__ cntA,
                                unsigned* __restrict__ wrongA, int N)
{
    const int r = blockIdx.x;
    unsigned c = cntA[r];
    float ub = (float)c / ((float)(N - (int)c) + 1e-6f);
    if (!(ub > 10.0f)) return;

    __shared__ float sQ[128];
    const int tid = threadIdx.x;
    if (tid < 128) sQ[tid] = Q[(size_t)r * 128 + tid];
    __syncthreads();

    const float inv_t = 1.0f / 0.07f;
    float m = bestA[r] * inv_t;
    float mean = (sumlA[r] - (float)c * m) / (float)N;
    int fl = flags[r];
    int wp = 0;
    for (int j = tid; j < N; j += 256) {
        float dot = 0.f;
        const float* kr = Kv + (size_t)j * 128;
        for (int k = 0; k < 128; ++k) dot += sQ[k] * kr[k];
        bool mask = (fl == qf[j]) && (fl != -1);
        float lfp = mask ? (dot * inv_t - m) : 0.f;
        if (lfp < mean) wp++;
    }
    atomicAdd(&wrongA[r], (unsigned)wp);
}

__global__ void final_kernel(const int* __restrict__ flags,
                             const int* __restrict__ qf,
                             const int* __restrict__ n_iter_p,
                             const float* __restrict__ bestA,
                             const int* __restrict__ jmaxA,
                             const float* __restrict__ sumlA,
                             const float* __restrict__ sumexpA,
                             const unsigned* __restrict__ cntA,
                             const unsigned* __restrict__ wrongA,
                             float* __restrict__ out, int N, int b)
{
    __shared__ float redf[1024];
    __shared__ unsigned redu[1024];
    const int r = threadIdx.x;
    const float inv_t = 1.0f / 0.07f;

    int fl = flags[r];
    float m = bestA[r] * inv_t;
    int jmax = jmaxA[r];
    float suml = sumlA[r];
    float sumexp = sumexpA[r];
    unsigned cnt = cntA[r];
    bool row_m1 = (fl == -1);
    int qmax = qf[jmax];

    float rowsum;
    if (row_m1) {
        rowsum = 0.f;  // row zeroed -> every exp==1 -> all excluded
    } else {
        float adj = sumexp;
        if (qmax != -1) adj -= __expf(m);  // exclude argmax (exp(l-m)==1)
        rowsum = __expf(-m) * adj;
        rowsum = fmaxf(rowsum, 0.f);
    }
    float sum_lfp = suml - (float)cnt * m;
    unsigned nnz = cnt - ((!row_m1 && fl == qmax) ? 1u : 0u);

    int nit = *n_iter_p;
    bool revise = false;
    if (nit >= 0) {
        float ub = (float)cnt / ((float)(N - (int)cnt) + 1e-6f);
        if (ub > 10.0f) {
            unsigned wr = wrongA[r];
            float wf = (float)wr;
            float pf = (float)(N - (int)wr);
            revise = (wf / (pf + 1e-6f)) > 10.0f;
        }
    }
    out[1 + r] = (float)(revise ? 0 : fl);
    float eff_suml = revise ? 0.f : sum_lfp;
    unsigned eff_nnz = revise ? 0u : nnz;

    redu[r] = eff_nnz;
    __syncthreads();
    for (int s = 512; s > 0; s >>= 1) {
        if (r < s) redu[r] += redu[r + s];
        __syncthreads();
    }
    unsigned total_nnz = redu[0];
    __syncthreads();

    float row_lp = eff_suml - (float)N * logf(rowsum + 1e-12f);
    float contrib = (total_nnz > 0u && rowsum > 0.f && row_lp < 0.f)
                        ? row_lp / (float)total_nnz
                        : 0.f;
    redf[r] = contrib;
    __syncthreads();
    for (int s = 512; s > 0; s >>= 1) {
        if (r < s) redf[r] += redf[r + s];
        __syncthreads();
    }
    if (r == 0) out[0] = -(redf[0] / (float)b);  // TEMP/BASE_TEMP == 1
}

extern "C" void kernel_launch(void* const* d_in, const int* in_sizes, int n_in,
                              void* d_out, int out_size, void* d_ws,
                              size_t ws_size, hipStream_t stream)
{
    const float* Q = (const float*)d_in[0];
    const float* Kall = (const float*)d_in[1];
    const int* flags = (const int*)d_in[2];
    const int* qfall = (const int*)d_in[3];
    const int* n_iter = (const int*)d_in[4];
    float* out = (float*)d_out;

    const int b = in_sizes[2];      // 1024
    const int total = in_sizes[3];  // 33792
    const int N = total - b;        // 32768
    const int NCB = N / 128;        // 256
    const float* Kv = Kall + (size_t)b * 128;
    const int* qf = qfall + b;

    char* wsb = (char*)d_ws;
    float* bestA = (float*)wsb;
    int* jmaxA = (int*)(wsb + 4096);
    float* sumlA = (float*)(wsb + 8192);
    float* sumexpA = (float*)(wsb + 12288);
    unsigned* cntA = (unsigned*)(wsb + 16384);
    unsigned* wrongA = (unsigned*)(wsb + 20480);
    // tier C only:
    unsigned long long* maxbits = (unsigned long long*)(wsb + 24576);
    // tier A/B partials (overlap maxbits; tiers are exclusive):
    float* pbest = (float*)(wsb + 24576);
    int* pbidx = (int*)(pbest + (size_t)NCB * b);
    float* pse = (float*)(pbidx + (size_t)NCB * b);
    float* psl = (float*)(pse + (size_t)NCB * b);
    unsigned* pcnt = (unsigned*)(psl + (size_t)NCB * b);
    unsigned short* Kb = (unsigned short*)(pcnt + (size_t)NCB * b);

    const size_t needB = 24576 + 5ull * NCB * b * 4;
    const size_t needA = needB + (size_t)N * 128 * 2;

    dim3 grid(NCB, b / 64);
    if (ws_size >= needA) {
        init_zero_kernel<<<(b + 255) / 256, 256, 0, stream>>>(wrongA, b);
        int n8k = N * 128 / 8;
        convert_kernel<<<(n8k + 255) / 256, 256, 0, stream>>>(Kv, Kb, n8k);
        gemm_kernel<true, false><<<grid, 256, 0, stream>>>(
            Q, Kv, Kb, flags, qf, pbest, pbidx, pse, psl, pcnt, maxbits,
            sumlA, sumexpA, cntA, N, b);
        reduce_kernel<<<b, 256, 0, stream>>>(pbest, pbidx, pse, psl, pcnt,
                                             bestA, jmaxA, sumlA, sumexpA,
                                             cntA, b);
    } else if (ws_size >= needB) {
        init_zero_kernel<<<(b + 255) / 256, 256, 0, stream>>>(wrongA, b);
        gemm_kernel<false, false><<<grid, 256, 0, stream>>>(
            Q, Kv, Kb, flags, qf, pbest, pbidx, pse, psl, pcnt, maxbits,
            sumlA, sumexpA, cntA, N, b);
        reduce_kernel<<<b, 256, 0, stream>>>(pbest, pbidx, pse, psl, pcnt,
                                             bestA, jmaxA, sumlA, sumexpA,
                                             cntA, b);
    } else {
        // tier C: zero suml/sumexp/cnt/wrong/maxbits (offsets 8KB..32KB)
        init_zero_kernel<<<(6 * b + 255) / 256, 256, 0, stream>>>(
            (unsigned*)(wsb + 8192), 6 * b);
        gemm_kernel<false, true><<<grid, 256, 0, stream>>>(
            Q, Kv, Kb, flags, qf, pbest, pbidx, pse, psl, pcnt, maxbits,
            sumlA, sumexpA, cntA, N, b);
        unpack_kernel<<<(b + 255) / 256, 256, 0, stream>>>(maxbits, bestA,
                                                           jmaxA, b);
    }
    fallback_kernel<<<b, 256, 0, stream>>>(Q, Kv, flags, qf, bestA, sumlA,
                                           cntA, wrongA, N);
    final_kernel<<<1, b, 0, stream>>>(flags, qf, n_iter, bestA, jmaxA, sumlA,
                                      sumexpA, cntA, wrongA, out, N, b);
}

// Round 4
// 69.310 us; speedup vs baseline: 5.4580x; 1.2354x over previous
//
#include <hip/hip_runtime.h>
#include <stdint.h>

// ---------------------------------------------------------------------------
// LIL loss, fused bf16-MFMA dot engine v3.
// Epilogue per row: max(dot)+2-bit class flag of the max element,
// sum exp2(dot*K2E) over qf!=-1, sum dot over {qf==fl, fl!=-1}.
// cnt per row via global histogram of qf. No atomics on the hot path.
// ws layout:
//   [0K)    bestA  f32[b]
//   [4K)    flagsA i32[b]      (0: qf@max notin {-1, fl}; 1: qf@max==-1; 2: qf@max==fl)
//   [8K)    sumlA  f32[b]      (sum of raw dots over positives)
//   [12K)   sumexpA f32[b]
//   [16K)   cntA   u32[b]
//   [20K)   wrongA u32[b]
//   [24K)   hist   u32[32]
//   [32K)   partials float4[NCB*b]  (4 MB)   {best, flag, se, sl}
//   [32K+4M) Kb bf16[N*128] (8 MB) | Qb bf16[b*128] (0.25 MB)   (tier A)
// ---------------------------------------------------------------------------

typedef short bf16x8 __attribute__((ext_vector_type(8)));
typedef unsigned short ushort8v __attribute__((ext_vector_type(8)));
typedef float f32x4 __attribute__((ext_vector_type(4)));

#define INV_T 14.285714285714286f          // 1/0.07
#define K2E   20.609929155698604f          // log2(e)/0.07

__device__ __forceinline__ unsigned short f2bf(float x) {
    unsigned u = __float_as_uint(x);
    return (unsigned short)((u + 0x7FFFu + ((u >> 16) & 1u)) >> 16);
}

__global__ void init_zero_kernel(unsigned* w, int nwords) {
    int i = blockIdx.x * blockDim.x + threadIdx.x;
    if (i < nwords) w[i] = 0u;
}

__global__ void convert_kernel(const float* __restrict__ src,
                               unsigned short* __restrict__ dst, int n8) {
    int i = blockIdx.x * blockDim.x + threadIdx.x;
    if (i >= n8) return;
    const float4* s4 = reinterpret_cast<const float4*>(src) + 2 * (size_t)i;
    float4 a = s4[0], b = s4[1];
    ushort8v v;
    v[0] = f2bf(a.x); v[1] = f2bf(a.y); v[2] = f2bf(a.z); v[3] = f2bf(a.w);
    v[4] = f2bf(b.x); v[5] = f2bf(b.y); v[6] = f2bf(b.z); v[7] = f2bf(b.w);
    *reinterpret_cast<ushort8v*>(dst + 8 * (size_t)i) = v;
}

__global__ void hist_kernel(const int* __restrict__ qf, unsigned* __restrict__ hist,
                            int N) {
    __shared__ unsigned lh[32];
    int t = threadIdx.x;
    if (t < 32) lh[t] = 0u;
    __syncthreads();
    for (int i = blockIdx.x * blockDim.x + t; i < N; i += gridDim.x * blockDim.x)
        atomicAdd(&lh[qf[i] + 1], 1u);
    __syncthreads();
    if (t < 32 && lh[t]) atomicAdd(&hist[t], lh[t]);
}

// C-tile 128(rows) x 128(cols), 8 waves, full K=128 in LDS (bf16, swizzled).
template <bool STAGE_WS>
__global__ __launch_bounds__(512) void gemm_kernel(
    const float* __restrict__ Qf, const float* __restrict__ Kf,
    const unsigned short* __restrict__ Qb, const unsigned short* __restrict__ Kb,
    const int* __restrict__ flags, const int* __restrict__ qf,
    float4* __restrict__ part, int N, int b)
{
    __shared__ __align__(16) unsigned short sA[128 * 128];  // 32 KB
    __shared__ __align__(16) unsigned short sB[128 * 128];  // 32 KB (reused)
    __shared__ int sFl[128];
    __shared__ int sQf[128];

    const int tid = threadIdx.x;
    const int c0 = blockIdx.x * 128;
    const int r0 = blockIdx.y * 128;
    char* sAb = (char*)sA;
    char* sBb = (char*)sB;

    // ---- stage A (Q rows) and B (K rows): 2048 8-elem chunks each
#pragma unroll
    for (int it = 0; it < 4; ++it) {
        int c = tid + it * 512;
        int row = c >> 4, kc = c & 15;
        int off = (row * 256 + kc * 16) ^ ((row & 7) << 4);
        if (STAGE_WS) {
            *reinterpret_cast<ushort8v*>(sAb + off) =
                *reinterpret_cast<const ushort8v*>(
                    Qb + (size_t)(r0 + row) * 128 + kc * 8);
        } else {
            const float4* s4 = reinterpret_cast<const float4*>(
                Qf + (size_t)(r0 + row) * 128 + kc * 8);
            float4 a = s4[0], bq = s4[1];
            ushort8v v;
            v[0] = f2bf(a.x); v[1] = f2bf(a.y); v[2] = f2bf(a.z); v[3] = f2bf(a.w);
            v[4] = f2bf(bq.x); v[5] = f2bf(bq.y); v[6] = f2bf(bq.z); v[7] = f2bf(bq.w);
            *reinterpret_cast<ushort8v*>(sAb + off) = v;
        }
    }
#pragma unroll
    for (int it = 0; it < 4; ++it) {
        int c = tid + it * 512;
        int row = c >> 4, kc = c & 15;
        int off = (row * 256 + kc * 16) ^ ((row & 7) << 4);
        if (STAGE_WS) {
            *reinterpret_cast<ushort8v*>(sBb + off) =
                *reinterpret_cast<const ushort8v*>(
                    Kb + (size_t)(c0 + row) * 128 + kc * 8);
        } else {
            const float4* s4 = reinterpret_cast<const float4*>(
                Kf + (size_t)(c0 + row) * 128 + kc * 8);
            float4 a = s4[0], bq = s4[1];
            ushort8v v;
            v[0] = f2bf(a.x); v[1] = f2bf(a.y); v[2] = f2bf(a.z); v[3] = f2bf(a.w);
            v[4] = f2bf(bq.x); v[5] = f2bf(bq.y); v[6] = f2bf(bq.z); v[7] = f2bf(bq.w);
            *reinterpret_cast<ushort8v*>(sBb + off) = v;
        }
    }
    if (tid < 128) sFl[tid] = flags[r0 + tid];
    if (tid < 128) sQf[tid] = qf[c0 + tid];
    __syncthreads();

    const int lane = tid & 63;
    const int g = lane >> 4;   // k-group
    const int q = lane & 15;   // row (A) / col (B) within fragment
    const int wave = tid >> 6;
    const int wr = wave >> 1;  // 0..3 row group of 32
    const int wc = wave & 1;   // 0..1 col group of 64

    f32x4 acc[2][4] = {};
#pragma unroll
    for (int ks = 0; ks < 4; ++ks) {
        const int kb = ks * 64 + g * 16;
        bf16x8 af[2];
#pragma unroll
        for (int mi = 0; mi < 2; ++mi) {
            int row = 32 * wr + 16 * mi + q;
            int off = (row * 256 + kb) ^ ((q & 7) << 4);
            af[mi] = *reinterpret_cast<const bf16x8*>(sAb + off);
        }
        bf16x8 bfr[4];
#pragma unroll
        for (int ni = 0; ni < 4; ++ni) {
            int col = 64 * wc + 16 * ni + q;
            int off = (col * 256 + kb) ^ ((q & 7) << 4);
            bfr[ni] = *reinterpret_cast<const bf16x8*>(sBb + off);
        }
#pragma unroll
        for (int mi = 0; mi < 2; ++mi)
#pragma unroll
            for (int ni = 0; ni < 4; ++ni)
                acc[mi][ni] = __builtin_amdgcn_mfma_f32_16x16x32_bf16(
                    af[mi], bfr[ni], acc[mi][ni], 0, 0, 0);
    }

    // per-ni column metadata
    int qv[4];
#pragma unroll
    for (int ni = 0; ni < 4; ++ni) qv[ni] = sQf[64 * wc + 16 * ni + q];

    __syncthreads();  // all MFMA LDS reads done; sB becomes scratch
    char* scratch = (char*)sB;  // [rl(128)][q'(16)] float4 records

    // phase 1: in-register reduce over 4 ni, write one record per (mi,reg)
#pragma unroll
    for (int mi = 0; mi < 2; ++mi) {
#pragma unroll
        for (int reg = 0; reg < 4; ++reg) {
            const int rl = 32 * wr + 16 * mi + 4 * g + reg;
            const int fl = sFl[rl];
            float best = -3.0e38f, bflg = 0.f, se = 0.f, sl = 0.f;
#pragma unroll
            for (int ni = 0; ni < 4; ++ni) {
                float dot = acc[mi][ni][reg];
                bool cm1 = (qv[ni] == -1);
                bool pos = (qv[ni] == fl) && (fl != -1);
                float e = exp2f(dot * K2E);
                se += cm1 ? 0.f : e;
                sl += pos ? dot : 0.f;
                float fladd = cm1 ? 1.f : (pos ? 2.f : 0.f);
                bool take = dot > best;
                best = take ? dot : best;
                bflg = take ? fladd : bflg;
            }
            f32x4 rec = {best, bflg, se, sl};
            int off = rl * 256 + ((q ^ (rl & 7)) << 4);
            *reinterpret_cast<f32x4*>(scratch + off) = rec;
        }
    }
    __syncthreads();

    // phase 2: fold 16 q-records per row: 4 threads/row x 4 records + quad shfl
    {
        const int row = tid >> 2, pgrp = tid & 3;
        float best = -3.0e38f, bflg = 0.f, se = 0.f, sl = 0.f;
#pragma unroll
        for (int i = 0; i < 4; ++i) {
            int qi = (pgrp * 4 + i) ^ (row & 7);
            f32x4 p = *reinterpret_cast<const f32x4*>(scratch + row * 256 + (qi << 4));
            bool take = p[0] > best;
            best = take ? p[0] : best;
            bflg = take ? p[1] : bflg;
            se += p[2];
            sl += p[3];
        }
#pragma unroll
        for (int off = 1; off < 4; off <<= 1) {
            float ob = __shfl_xor(best, off);
            float of = __shfl_xor(bflg, off);
            float os = __shfl_xor(se, off);
            float ol = __shfl_xor(sl, off);
            bool take = ob > best;
            best = take ? ob : best;
            bflg = take ? of : bflg;
            se += os;
            sl += ol;
        }
        if (pgrp == 0)
            part[(size_t)blockIdx.x * b + r0 + row] =
                make_float4(best, bflg, se, sl);
    }
}

// 16 blocks x 64 rows: fold NCB partials per row, fully coalesced.
__global__ __launch_bounds__(256) void reduce_kernel(
    const float4* __restrict__ part, const int* __restrict__ flags,
    const unsigned* __restrict__ hist, float* __restrict__ bestA,
    int* __restrict__ flagsA, float* __restrict__ sumlA,
    float* __restrict__ sumexpA, unsigned* __restrict__ cntA, int NCB, int b)
{
    const int t = threadIdx.x;
    const int rl = t & 63;
    const int r = blockIdx.x * 64 + rl;
    const int pgrp = t >> 6;
    float best = -3.0e38f, bflg = 0.f, se = 0.f, sl = 0.f;
    for (int cb = pgrp; cb < NCB; cb += 4) {
        float4 p = part[(size_t)cb * b + r];
        bool take = p.x > best;
        best = take ? p.x : best;
        bflg = take ? p.y : bflg;
        se += p.z;
        sl += p.w;
    }
    __shared__ float4 lred[4][64];
    lred[pgrp][rl] = make_float4(best, bflg, se, sl);
    __syncthreads();
    if (t < 64) {
        const int rr = blockIdx.x * 64 + t;
        best = -3.0e38f; bflg = 0.f; se = 0.f; sl = 0.f;
#pragma unroll
        for (int i = 0; i < 4; ++i) {
            float4 p = lred[i][t];
            bool take = p.x > best;
            best = take ? p.x : best;
            bflg = take ? p.y : bflg;
            se += p.z;
            sl += p.w;
        }
        bestA[rr] = best;
        flagsA[rr] = (int)bflg;
        sumexpA[rr] = se;
        sumlA[rr] = sl;
        int fl = flags[rr];
        cntA[rr] = (fl >= 0) ? hist[fl + 1] : 0u;
    }
}

// Exact wrong_cnt insurance; early-exits unless a row could possibly revise.
__global__ void fallback_kernel(const float* __restrict__ Q,
                                const float* __restrict__ Kv,
                                const int* __restrict__ flags,
                                const int* __restrict__ qf,
                                const float* __restrict__ bestA,
                                const float* __restrict__ sumlA,
                                const unsigned* __restrict__ cntA,
                                unsigned* __restrict__ wrongA, int N)
{
    const int r = blockIdx.x;
    unsigned c = cntA[r];
    float ub = (float)c / ((float)(N - (int)c) + 1e-6f);
    if (!(ub > 10.0f)) return;

    __shared__ float sQ[128];
    const int tid = threadIdx.x;
    if (tid < 128) sQ[tid] = Q[(size_t)r * 128 + tid];
    __syncthreads();

    float m = bestA[r] * INV_T;
    float mean = (INV_T * sumlA[r] - (float)c * m) / (float)N;
    int fl = flags[r];
    int wp = 0;
    for (int j = tid; j < N; j += 256) {
        float dot = 0.f;
        const float* kr = Kv + (size_t)j * 128;
        for (int k = 0; k < 128; ++k) dot += sQ[k] * kr[k];
        bool mask = (fl == qf[j]) && (fl != -1);
        float lfp = mask ? (dot * INV_T - m) : 0.f;
        if (lfp < mean) wp++;
    }
    atomicAdd(&wrongA[r], (unsigned)wp);
}

__global__ void final_kernel(const int* __restrict__ flags,
                             const int* __restrict__ n_iter_p,
                             const float* __restrict__ bestA,
                             const int* __restrict__ flagsA,
                             const float* __restrict__ sumlA,
                             const float* __restrict__ sumexpA,
                             const unsigned* __restrict__ cntA,
                             const unsigned* __restrict__ wrongA,
                             float* __restrict__ out, int N, int b)
{
    __shared__ float redf[1024];
    __shared__ unsigned redu[1024];
    const int r = threadIdx.x;

    int fl = flags[r];
    bool row_m1 = (fl == -1);
    float mdot = bestA[r];
    float m = mdot * INV_T;
    int bits = flagsA[r];
    float se = sumexpA[r];
    float sl = sumlA[r];
    unsigned cnt = cntA[r];

    float rowsum;
    if (row_m1) {
        rowsum = 0.f;  // row zeroed -> every exp==1 -> all excluded
    } else {
        float adj = se - ((bits == 1) ? 0.f : exp2f(mdot * K2E));
        rowsum = exp2f(-mdot * K2E) * adj;
        rowsum = fmaxf(rowsum, 0.f);
    }
    float sum_lfp = INV_T * sl - (float)cnt * m;
    unsigned nnz = cnt - ((bits == 2) ? 1u : 0u);

    int nit = *n_iter_p;
    bool revise = false;
    if (nit >= 0) {
        float ub = (float)cnt / ((float)(N - (int)cnt) + 1e-6f);
        if (ub > 10.0f) {
            unsigned wr = wrongA[r];
            float wf = (float)wr;
            float pf = (float)(N - (int)wr);
            revise = (wf / (pf + 1e-6f)) > 10.0f;
        }
    }
    out[1 + r] = (float)(revise ? 0 : fl);
    float eff_suml = revise ? 0.f : sum_lfp;
    unsigned eff_nnz = revise ? 0u : nnz;

    redu[r] = eff_nnz;
    __syncthreads();
    for (int s = 512; s > 0; s >>= 1) {
        if (r < s) redu[r] += redu[r + s];
        __syncthreads();
    }
    unsigned total_nnz = redu[0];
    __syncthreads();

    float row_lp = eff_suml - (float)N * logf(rowsum + 1e-12f);
    float contrib = (total_nnz > 0u && rowsum > 0.f && row_lp < 0.f)
                        ? row_lp / (float)total_nnz
                        : 0.f;
    redf[r] = contrib;
    __syncthreads();
    for (int s = 512; s > 0; s >>= 1) {
        if (r < s) redf[r] += redf[r + s];
        __syncthreads();
    }
    if (r == 0) out[0] = -(redf[0] / (float)b);  // TEMP/BASE_TEMP == 1
}

extern "C" void kernel_launch(void* const* d_in, const int* in_sizes, int n_in,
                              void* d_out, int out_size, void* d_ws,
                              size_t ws_size, hipStream_t stream)
{
    const float* Q = (const float*)d_in[0];
    const float* Kall = (const float*)d_in[1];
    const int* flags = (const int*)d_in[2];
    const int* qfall = (const int*)d_in[3];
    const int* n_iter = (const int*)d_in[4];
    float* out = (float*)d_out;

    const int b = in_sizes[2];      // 1024
    const int total = in_sizes[3];  // 33792
    const int N = total - b;        // 32768
    const int NCB = N / 128;        // 256
    const float* Kv = Kall + (size_t)b * 128;
    const int* qf = qfall + b;

    char* wsb = (char*)d_ws;
    float* bestA = (float*)wsb;
    int* flagsA = (int*)(wsb + 4096);
    float* sumlA = (float*)(wsb + 8192);
    float* sumexpA = (float*)(wsb + 12288);
    unsigned* cntA = (unsigned*)(wsb + 16384);
    unsigned* wrongA = (unsigned*)(wsb + 20480);
    unsigned* hist = (unsigned*)(wsb + 24576);
    float4* part = (float4*)(wsb + 32768);
    unsigned short* Kb = (unsigned short*)(wsb + 32768 + (size_t)NCB * b * 16);
    unsigned short* Qb = Kb + (size_t)N * 128;

    const size_t needB = 32768 + (size_t)NCB * b * 16;
    const size_t needA = needB + ((size_t)N + b) * 128 * 2;

    // zero wrongA (4KB) + hist (128B): contiguous from offset 20480
    init_zero_kernel<<<(1056 + 255) / 256, 256, 0, stream>>>(
        (unsigned*)(wsb + 20480), 1056);
    hist_kernel<<<64, 256, 0, stream>>>(qf, hist, N);

    dim3 grid(NCB, b / 128);
    if (ws_size >= needA) {
        int n8k = N * 128 / 8;
        convert_kernel<<<(n8k + 255) / 256, 256, 0, stream>>>(Kv, Kb, n8k);
        int n8q = b * 128 / 8;
        convert_kernel<<<(n8q + 255) / 256, 256, 0, stream>>>(Q, Qb, n8q);
        gemm_kernel<true><<<grid, 512, 0, stream>>>(Q, Kv, Qb, Kb, flags, qf,
                                                    part, N, b);
    } else {
        gemm_kernel<false><<<grid, 512, 0, stream>>>(Q, Kv, Qb, Kb, flags, qf,
                                                     part, N, b);
    }
    reduce_kernel<<<b / 64, 256, 0, stream>>>(part, flags, hist, bestA, flagsA,
                                              sumlA, sumexpA, cntA, NCB, b);
    fallback_kernel<<<b, 256, 0, stream>>>(Q, Kv, flags, qf, bestA, sumlA,
                                           cntA, wrongA, N);
    final_kernel<<<1, b, 0, stream>>>(flags, n_iter, bestA, flagsA, sumlA,
                                      sumexpA, cntA, wrongA, out, N, b);
}